// Round 5
// baseline (491.172 us; speedup 1.0000x reference)
//
#include <hip/hip_runtime.h>
#include <hip/hip_bf16.h>
#include <math.h>

#define NN     4
#define C1c    128
#define C2c    36
#define Hc     192
#define Wc     192
#define HOc    190
#define WOc    190
#define HWc    (Hc*Wc)        // 36864
#define HWO    (HOc*WOc)      // 36100

using v8s = __attribute__((ext_vector_type(8))) short;
using v4i = __attribute__((ext_vector_type(4))) int;
using v4f = __attribute__((ext_vector_type(4))) float;

__device__ __forceinline__ unsigned short f2bf(float f) {
    __hip_bfloat16 h = __float2bfloat16(f);
    return __builtin_bit_cast(unsigned short, h);
}

// ---------------- x: NCHW fp32 -> NHWC bf16 ------------------------------
__global__ void x_to_nhwc(const float* __restrict__ x, unsigned short* __restrict__ xt) {
    __shared__ float tile[64 * 129];
    const int tid = threadIdx.x;
    const int w0  = blockIdx.x * 64;
    const int h   = blockIdx.y;
    const int n   = blockIdx.z;
    {
        const int w  = tid & 63, cb = tid >> 6;
        const float* xp = x + ((size_t)n * C1c * Hc + h) * Wc + w0 + w;
        #pragma unroll
        for (int i = 0; i < 32; ++i) {
            int c = cb + i * 4;
            tile[w * 129 + c] = xp[(size_t)c * HWc];
        }
    }
    __syncthreads();
    {
        const int c2 = tid & 127, wb2l = tid >> 7;
        unsigned short* op = xt + ((size_t)((n * Hc + h) * Wc) + w0) * C1c + c2;
        #pragma unroll
        for (int j = 0; j < 32; ++j) {
            int ww = wb2l + j * 2;
            op[(size_t)ww * C1c] = f2bf(tile[ww * 129 + c2]);
        }
    }
}

// ---------------- deform_w -> bf16 A-fragment layout (permuted K) ---------
__global__ void w_prep2(const float* __restrict__ dw, unsigned short* __restrict__ wb2) {
    int i = blockIdx.x * 256 + threadIdx.x;
    if (i >= 9 * 3 * 4 * 64 * 8) return;
    int j    = i & 7;
    int lane = (i >> 3) & 63;
    int s    = (i >> 9) & 3;
    int rem  = i >> 11;            // tap*3 + oblk
    int oblk = rem % 3;
    int tap  = rem / 3;
    int quad = (lane >> 4) & 3;
    int o = oblk * 16 + (lane & 15);
    int c = (quad >> 1) * 64 + s * 16 + (quad & 1) * 8 + j;
    float v = (o < 36) ? dw[((size_t)o * C1c + c) * 9 + tap] : 0.f;
    wb2[i] = f2bf(v);
}

// ---------------- conv_w -> cwT[(g*32+ci)*84 + oo*9+tt] (rows padded) -----
__global__ void cw_prep(const float* __restrict__ cw, float* __restrict__ cwT) {
    int i = blockIdx.x * 256 + threadIdx.x;
    if (i >= 4 * 32 * 84) return;
    int r   = i / 84;          // g*32+ci
    int idx = i - r * 84;
    int g = r >> 5, ci = r & 31;
    float v = 0.f;
    if (idx < 81) {
        int oo = idx / 9, tt = idx - oo * 9;
        int o  = g * 9 + oo;
        v = cw[(o * 32 + ci) * 9 + tt];
    }
    cwT[i] = v;
}

// ---------------- offset conv: interleaved (dy,dx) output -----------------
__launch_bounds__(256, 8)
__global__ void dcn_offsets(const float* __restrict__ x,
                            const float* __restrict__ cwT,
                            float* __restrict__ offi) {
    const int tid = threadIdx.x;
    const int n   = blockIdx.z >> 2;
    const int g   = blockIdx.z & 3;
    int wo = blockIdx.x * 64 + (tid & 63);
    int ho = blockIdx.y * 4  + (tid >> 6);
    const bool active = (wo < WOc) && (ho < HOc);
    if (wo > WOc - 1) wo = WOc - 1;
    if (ho > HOc - 1) ho = HOc - 1;

    float offv[9];
    #pragma unroll
    for (int oo = 0; oo < 9; ++oo) offv[oo] = 0.f;

    const float* xp0 = x + ((size_t)n * C1c + g * 32) * HWc + ho * Wc + wo;
    const float* wr0 = cwT + (size_t)g * 32 * 84;
    #pragma unroll 1
    for (int ci = 0; ci < 32; ++ci) {
        const float* xp = xp0 + (size_t)ci * HWc;
        float xv[9];
        #pragma unroll
        for (int i = 0; i < 3; ++i)
            #pragma unroll
            for (int j = 0; j < 3; ++j)
                xv[i * 3 + j] = xp[i * Wc + j];
        const float* wr = wr0 + ci * 84;   // wave-uniform -> s_load
        #pragma unroll
        for (int oo = 0; oo < 9; ++oo) {
            float a = offv[oo];
            #pragma unroll
            for (int tt = 0; tt < 9; ++tt)
                a = fmaf(xv[tt], wr[oo * 9 + tt], a);
            offv[oo] = a;
        }
    }

    if (active) {
        const int px = ho * WOc + wo;
        float* base = offi + (size_t)n * 18 * HWO * 2;
        #pragma unroll
        for (int oo = 0; oo < 9; ++oo) {
            int og = g * 9 + oo;
            int dg = og / 18;
            int r  = og - dg * 18;
            int tt = r >> 1;
            int cc = r & 1;
            base[(((size_t)dg * 9 + tt) * HWO + px) * 2 + cc] = offv[oo];
        }
    }
}

// ---------------- main: s-phase pipelined gather + MFMA + BN/Mish ---------
// 36 phases (9 taps x 4 s-steps). Rolling 3-buffer, lookahead = 2 phases:
// phase J issues loads for phase J+2, then consumes phase J. All buffer /
// address-slot indices are compile-time (taps mod 3 within a 3-tap loop).
// waves-per-eu=6: occupancy tracks this attr (R2: 8->60%, R3/R4: 4->40%);
// VGPR budget 512/6=85 keeps the 64-VGPR pipeline un-squeezed.
__launch_bounds__(256, 6)
__global__ void dcn_mfma(const unsigned short* __restrict__ xt,
                         const unsigned short* __restrict__ wb2,
                         const float* __restrict__ offi,
                         const float* __restrict__ bn_gamma,
                         const float* __restrict__ bn_beta,
                         const float* __restrict__ bn_mean,
                         const float* __restrict__ bn_var,
                         float* __restrict__ out) {
    const int tid  = threadIdx.x;
    const int lane = tid & 63;
    const int wave = tid >> 6;

    // XCD-contiguous decode: each XCD owns 283 consecutive (n,strip) slots.
    int gs = (blockIdx.x & 7) * 283 + (blockIdx.x >> 3);
    if (gs > NN * 565 - 1) gs = NN * 565 - 1;
    const int n     = gs / 565;
    const int strip = gs - n * 565;
    const int pxb   = strip * 64 + wave * 16;

    const int pi    = lane & 15;        // px within wave tile
    const int dgl   = lane >> 5;        // deformable group
    const int qlow  = (lane >> 4) & 1;
    const int kgoff = dgl * 128 + qlow * 16;
    int pxs = pxb + pi;
    if (pxs > HWO - 1) pxs = HWO - 1;
    const int ho = pxs / 190;
    const int wo = pxs - ho * 190;

    const float* offp = offi + ((size_t)(n * 2 + dgl) * 9) * HWO * 2 + (size_t)pxs * 2;
    const char*  xbc  = (const char*)(xt + (size_t)n * HWc * C1c);

    v4f acc0 = {0.f,0.f,0.f,0.f}, acc1 = {0.f,0.f,0.f,0.f}, acc2 = {0.f,0.f,0.f,0.f};

    // Pipeline state. All indices below are compile-time constants.
    float2 dpre[3];      // offset (dy,dx) for taps, slot = tap % 3
    int    vaT[3][4];    // corner byte offsets, slot = tap % 3
    float  wT[3][4];     // corner weights,      slot = tap % 3
    v4i    qb[3][4];     // gather buffers,      slot = phase % 3

    dpre[0] = *(const float2*)(offp + 0 * HWO * 2);
    dpre[1] = *(const float2*)(offp + 1 * HWO * 2);

// Corner math for tap TT into slot SLOT (= TT%3); prefetch d for tap TT+2.
#define PREPT(SLOT, TT) do {                                                   \
    const int t_ = (TT);                                                       \
    const int ki_ = t_ / 3, kj_ = t_ - (t_ / 3) * 3;                           \
    float2 dv_ = dpre[SLOT];                                                   \
    float py_  = (float)(ho + ki_) + dv_.x;                                    \
    float pxf_ = (float)(wo + kj_) + dv_.y;                                    \
    float fy0_ = floorf(py_), fx0_ = floorf(pxf_);                             \
    float wy_ = py_ - fy0_, wx_ = pxf_ - fx0_;                                 \
    float fy1_ = fy0_ + 1.f, fx1_ = fx0_ + 1.f;                                \
    bool vy0_ = (fy0_ >= 0.f) && (fy0_ <= (float)(Hc - 1));                    \
    bool vy1_ = (fy1_ >= 0.f) && (fy1_ <= (float)(Hc - 1));                    \
    bool vx0_ = (fx0_ >= 0.f) && (fx0_ <= (float)(Wc - 1));                    \
    bool vx1_ = (fx1_ >= 0.f) && (fx1_ <= (float)(Wc - 1));                    \
    int iy0_ = min(max((int)fy0_, 0), Hc - 1);                                 \
    int iy1_ = min(max((int)fy1_, 0), Hc - 1);                                 \
    int ix0_ = min(max((int)fx0_, 0), Wc - 1);                                 \
    int ix1_ = min(max((int)fx1_, 0), Wc - 1);                                 \
    wT[SLOT][0] = (vy0_ && vx0_) ? (1.f - wy_) * (1.f - wx_) : 0.f;            \
    wT[SLOT][1] = (vy0_ && vx1_) ? (1.f - wy_) * wx_         : 0.f;            \
    wT[SLOT][2] = (vy1_ && vx0_) ? wy_ * (1.f - wx_)         : 0.f;            \
    wT[SLOT][3] = (vy1_ && vx1_) ? wy_ * wx_                 : 0.f;            \
    vaT[SLOT][0] = (iy0_ * Wc + ix0_) * 256 + kgoff;                           \
    vaT[SLOT][1] = (iy0_ * Wc + ix1_) * 256 + kgoff;                           \
    vaT[SLOT][2] = (iy1_ * Wc + ix0_) * 256 + kgoff;                           \
    vaT[SLOT][3] = (iy1_ * Wc + ix1_) * 256 + kgoff;                           \
    if (t_ + 2 <= 8)                                                           \
        dpre[((SLOT) + 2) % 3] = *(const float2*)(offp + (size_t)(t_ + 2) * HWO * 2); \
} while (0)

// Issue the 4 corner gathers of (tap slot SLOT, s SS) into buffer BUF.
#define ISSUEP(BUF, SLOT, SS) do {                                             \
    qb[BUF][0] = *(const v4i*)(xbc + vaT[SLOT][0] + (SS) * 32);                \
    qb[BUF][1] = *(const v4i*)(xbc + vaT[SLOT][1] + (SS) * 32);                \
    qb[BUF][2] = *(const v4i*)(xbc + vaT[SLOT][2] + (SS) * 32);                \
    qb[BUF][3] = *(const v4i*)(xbc + vaT[SLOT][3] + (SS) * 32);                \
} while (0)

// Blend one packed bf16 pair (element JJ) of buffer BUF; pack via cvt_pk.
#define BLEND1(BUF, JJ, DST) do {                                              \
    int u0_ = qb[BUF][0][JJ], u1_ = qb[BUF][1][JJ];                            \
    int u2_ = qb[BUF][2][JJ], u3_ = qb[BUF][3][JJ];                            \
    float l0_ = __builtin_bit_cast(float, u0_ << 16);                          \
    float l1_ = __builtin_bit_cast(float, u1_ << 16);                          \
    float l2_ = __builtin_bit_cast(float, u2_ << 16);                          \
    float l3_ = __builtin_bit_cast(float, u3_ << 16);                          \
    float h0_ = __builtin_bit_cast(float, (int)(u0_ & 0xffff0000));            \
    float h1_ = __builtin_bit_cast(float, (int)(u1_ & 0xffff0000));            \
    float h2_ = __builtin_bit_cast(float, (int)(u2_ & 0xffff0000));            \
    float h3_ = __builtin_bit_cast(float, (int)(u3_ & 0xffff0000));            \
    float v0_ = fmaf(W3_, l3_, fmaf(W2_, l2_, fmaf(W1_, l1_, W0_ * l0_)));     \
    float v1_ = fmaf(W3_, h3_, fmaf(W2_, h2_, fmaf(W1_, h1_, W0_ * h0_)));     \
    int r_;                                                                    \
    asm("v_cvt_pk_bf16_f32 %0, %1, %2" : "=v"(r_) : "v"(v0_), "v"(v1_));       \
    (DST) = r_;                                                                \
} while (0)

// Consume buffer BUF for (tap slot SLOT, s SS); TRT = runtime tap index.
#define CONSUMEP(BUF, SLOT, SS, TRT) do {                                      \
    const unsigned short* wtap_ = wb2 + (size_t)(TRT) * 6144;                  \
    float W0_ = wT[SLOT][0], W1_ = wT[SLOT][1];                                \
    float W2_ = wT[SLOT][2], W3_ = wT[SLOT][3];                                \
    v4i bi_;                                                                   \
    BLEND1(BUF, 0, bi_[0]);                                                    \
    BLEND1(BUF, 1, bi_[1]);                                                    \
    BLEND1(BUF, 2, bi_[2]);                                                    \
    BLEND1(BUF, 3, bi_[3]);                                                    \
    v8s bfrag_ = __builtin_bit_cast(v8s, bi_);                                 \
    v8s a0_ = *(const v8s*)(wtap_ + (0 * 4 + (SS)) * 512 + lane * 8);          \
    v8s a1_ = *(const v8s*)(wtap_ + (1 * 4 + (SS)) * 512 + lane * 8);          \
    v8s a2_ = *(const v8s*)(wtap_ + (2 * 4 + (SS)) * 512 + lane * 8);          \
    acc0 = __builtin_amdgcn_mfma_f32_16x16x32_bf16(a0_, bfrag_, acc0, 0, 0, 0);\
    acc1 = __builtin_amdgcn_mfma_f32_16x16x32_bf16(a1_, bfrag_, acc1, 0, 0, 0);\
    acc2 = __builtin_amdgcn_mfma_f32_16x16x32_bf16(a2_, bfrag_, acc2, 0, 0, 0);\
} while (0)

// Phase J of the 12-phase (3-tap) loop body. Issues phase J+2, consumes J.
// Prep runs just before the first issue of a new tap ((J+2)%4 == 0).
#define PHASE(J) do {                                                          \
    if ((J) == 2)  PREPT(1, tq3 + 1);                                          \
    if ((J) == 6)  PREPT(2, tq3 + 2);                                          \
    if ((J) == 10) { if (tq < 2) PREPT(0, tq3 + 3); }                          \
    if ((J) <= 9 || tq < 2)                                                    \
        ISSUEP(((J) + 2) % 3, (((J) + 2) >> 2) % 3, ((J) + 2) & 3);            \
    __builtin_amdgcn_sched_barrier(0);                                         \
    CONSUMEP((J) % 3, (J) >> 2, (J) & 3, tq3 + ((J) >> 2));                    \
} while (0)

    // Prologue: prep tap 0, pre-issue phases 0 and 1.
    PREPT(0, 0);
    ISSUEP(0, 0, 0);
    ISSUEP(1, 0, 1);

    #pragma unroll 1
    for (int tq = 0; tq < 3; ++tq) {
        const int tq3 = tq * 3;
        PHASE(0);  PHASE(1);  PHASE(2);  PHASE(3);
        PHASE(4);  PHASE(5);  PHASE(6);  PHASE(7);
        PHASE(8);  PHASE(9);  PHASE(10); PHASE(11);
    }

#undef PHASE
#undef CONSUMEP
#undef BLEND1
#undef ISSUEP
#undef PREPT

    // ---- epilogue: BN + Mish; C layout col=lane&15 (px), row=quad*4+reg (o)
    const int col  = lane & 15;
    const int rowq = ((lane >> 4) & 3) * 4;
    const int pxo  = pxb + col;
    if (pxo < HWO) {
        v4f accs[3] = {acc0, acc1, acc2};
        #pragma unroll
        for (int ot = 0; ot < 3; ++ot) {
            #pragma unroll
            for (int r = 0; r < 4; ++r) {
                int o = ot * 16 + rowq + r;
                if (o < 36) {
                    float inv = bn_gamma[o] * rsqrtf(bn_var[o] + 1e-5f);
                    float b   = bn_beta[o] - bn_mean[o] * inv;
                    float v   = fmaf(accs[ot][r], inv, b);
                    float sp  = (v > 20.f) ? v : log1pf(__expf(v));
                    float e2  = __expf(-2.f * sp);
                    float th  = (1.f - e2) / (1.f + e2);
                    out[((size_t)n * 36 + o) * HWO + pxo] = v * th;
                }
            }
        }
    }
}

extern "C" void kernel_launch(void* const* d_in, const int* in_sizes, int n_in,
                              void* d_out, int out_size, void* d_ws, size_t ws_size,
                              hipStream_t stream) {
    (void)in_sizes; (void)n_in; (void)out_size; (void)ws_size;
    const float* x        = (const float*)d_in[0];
    const float* conv_w   = (const float*)d_in[1];
    const float* deform_w = (const float*)d_in[2];
    const float* bn_gamma = (const float*)d_in[3];
    const float* bn_beta  = (const float*)d_in[4];
    const float* bn_mean  = (const float*)d_in[5];
    const float* bn_var   = (const float*)d_in[6];
    float* out = (float*)d_out;

    float*          offi = (float*)d_ws;                                     // 20.8 MB
    unsigned short* xt   = (unsigned short*)(offi + (size_t)NN * 36 * HWO);  // 37.7 MB
    unsigned short* wbp2 = xt + (size_t)NN * HWc * C1c;                      // 110.6 KB
    float*          cwT  = (float*)(wbp2 + (size_t)9 * 3 * 4 * 64 * 8);      // 43 KB

    x_to_nhwc<<<dim3(3, 192, 4), 256, 0, stream>>>(x, xt);
    w_prep2<<<216, 256, 0, stream>>>(deform_w, wbp2);
    cw_prep<<<42, 256, 0, stream>>>(conv_w, cwT);
    dcn_offsets<<<dim3(3, 48, 16), 256, 0, stream>>>(x, cwT, offi);
    dcn_mfma<<<dim3(8 * 283, 1), 256, 0, stream>>>(xt, wbp2, offi,
                                                   bn_gamma, bn_beta, bn_mean, bn_var, out);
}

// Round 6
// 355.039 us; speedup vs baseline: 1.3834x; 1.3834x over previous
//
#include <hip/hip_runtime.h>
#include <hip/hip_bf16.h>
#include <math.h>

#define NN     4
#define C1c    128
#define C2c    36
#define Hc     192
#define Wc     192
#define HOc    190
#define WOc    190
#define HWc    (Hc*Wc)        // 36864
#define HWO    (HOc*WOc)      // 36100

using v8s = __attribute__((ext_vector_type(8))) short;
using v4i = __attribute__((ext_vector_type(4))) int;
using v4f = __attribute__((ext_vector_type(4))) float;

__device__ __forceinline__ unsigned short f2bf(float f) {
    __hip_bfloat16 h = __float2bfloat16(f);
    return __builtin_bit_cast(unsigned short, h);
}

// ---------------- x: NCHW fp32 -> NHWC bf16 ------------------------------
__global__ void x_to_nhwc(const float* __restrict__ x, unsigned short* __restrict__ xt) {
    __shared__ float tile[64 * 129];
    const int tid = threadIdx.x;
    const int w0  = blockIdx.x * 64;
    const int h   = blockIdx.y;
    const int n   = blockIdx.z;
    {
        const int w  = tid & 63, cb = tid >> 6;
        const float* xp = x + ((size_t)n * C1c * Hc + h) * Wc + w0 + w;
        #pragma unroll
        for (int i = 0; i < 32; ++i) {
            int c = cb + i * 4;
            tile[w * 129 + c] = xp[(size_t)c * HWc];
        }
    }
    __syncthreads();
    {
        const int c2 = tid & 127, wb2l = tid >> 7;
        unsigned short* op = xt + ((size_t)((n * Hc + h) * Wc) + w0) * C1c + c2;
        #pragma unroll
        for (int j = 0; j < 32; ++j) {
            int ww = wb2l + j * 2;
            op[(size_t)ww * C1c] = f2bf(tile[ww * 129 + c2]);
        }
    }
}

// ---------------- deform_w -> bf16 A-fragment layout (permuted K) ---------
__global__ void w_prep2(const float* __restrict__ dw, unsigned short* __restrict__ wb2) {
    int i = blockIdx.x * 256 + threadIdx.x;
    if (i >= 9 * 3 * 4 * 64 * 8) return;
    int j    = i & 7;
    int lane = (i >> 3) & 63;
    int s    = (i >> 9) & 3;
    int rem  = i >> 11;            // tap*3 + oblk
    int oblk = rem % 3;
    int tap  = rem / 3;
    int quad = (lane >> 4) & 3;
    int o = oblk * 16 + (lane & 15);
    int c = (quad >> 1) * 64 + s * 16 + (quad & 1) * 8 + j;
    float v = (o < 36) ? dw[((size_t)o * C1c + c) * 9 + tap] : 0.f;
    wb2[i] = f2bf(v);
}

// ---------------- conv_w -> cwT[(g*32+ci)*84 + oo*9+tt] (rows padded) -----
__global__ void cw_prep(const float* __restrict__ cw, float* __restrict__ cwT) {
    int i = blockIdx.x * 256 + threadIdx.x;
    if (i >= 4 * 32 * 84) return;
    int r   = i / 84;          // g*32+ci
    int idx = i - r * 84;
    int g = r >> 5, ci = r & 31;
    float v = 0.f;
    if (idx < 81) {
        int oo = idx / 9, tt = idx - oo * 9;
        int o  = g * 9 + oo;
        v = cw[(o * 32 + ci) * 9 + tt];
    }
    cwT[i] = v;
}

// ---------------- offset conv: interleaved (dy,dx) output -----------------
__launch_bounds__(256, 8)
__global__ void dcn_offsets(const float* __restrict__ x,
                            const float* __restrict__ cwT,
                            float* __restrict__ offi) {
    const int tid = threadIdx.x;
    const int n   = blockIdx.z >> 2;
    const int g   = blockIdx.z & 3;
    int wo = blockIdx.x * 64 + (tid & 63);
    int ho = blockIdx.y * 4  + (tid >> 6);
    const bool active = (wo < WOc) && (ho < HOc);
    if (wo > WOc - 1) wo = WOc - 1;
    if (ho > HOc - 1) ho = HOc - 1;

    float offv[9];
    #pragma unroll
    for (int oo = 0; oo < 9; ++oo) offv[oo] = 0.f;

    const float* xp0 = x + ((size_t)n * C1c + g * 32) * HWc + ho * Wc + wo;
    const float* wr0 = cwT + (size_t)g * 32 * 84;
    #pragma unroll 1
    for (int ci = 0; ci < 32; ++ci) {
        const float* xp = xp0 + (size_t)ci * HWc;
        float xv[9];
        #pragma unroll
        for (int i = 0; i < 3; ++i)
            #pragma unroll
            for (int j = 0; j < 3; ++j)
                xv[i * 3 + j] = xp[i * Wc + j];
        const float* wr = wr0 + ci * 84;   // wave-uniform -> s_load
        #pragma unroll
        for (int oo = 0; oo < 9; ++oo) {
            float a = offv[oo];
            #pragma unroll
            for (int tt = 0; tt < 9; ++tt)
                a = fmaf(xv[tt], wr[oo * 9 + tt], a);
            offv[oo] = a;
        }
    }

    if (active) {
        const int px = ho * WOc + wo;
        float* base = offi + (size_t)n * 18 * HWO * 2;
        #pragma unroll
        for (int oo = 0; oo < 9; ++oo) {
            int og = g * 9 + oo;
            int dg = og / 18;
            int r  = og - dg * 18;
            int tt = r >> 1;
            int cc = r & 1;
            base[(((size_t)dg * 9 + tt) * HWO + px) * 2 + cc] = offv[oo];
        }
    }
}

// ---------------- main: s-phase pipelined gather + MFMA + BN/Mish ---------
// 36 phases (9 taps x 4 s-steps). Rolling 3-buffer, lookahead = 2 phases:
// phase J issues loads for phase J+2, then consumes phase J. All buffer /
// address-slot indices are compile-time (taps mod 3 within a 3-tap loop).
// NO __launch_bounds__: the waves-per-eu attr both caps residency (attr ~
// wg/CU) and halves the arch-VGPR budget 50/50 vs AGPR (R2/R4/R5 data:
// attr=8->32, attr=6->40+spill, attr=4->64 arch VGPRs). Declaring only the
// exact block shape lets the allocator keep the pipeline's natural register
// count and lets HW set residency from actual usage.
__attribute__((amdgpu_flat_work_group_size(256, 256)))
__global__ void dcn_mfma(const unsigned short* __restrict__ xt,
                         const unsigned short* __restrict__ wb2,
                         const float* __restrict__ offi,
                         const float* __restrict__ bn_gamma,
                         const float* __restrict__ bn_beta,
                         const float* __restrict__ bn_mean,
                         const float* __restrict__ bn_var,
                         float* __restrict__ out) {
    const int tid  = threadIdx.x;
    const int lane = tid & 63;
    const int wave = tid >> 6;

    // XCD-contiguous decode: each XCD owns 283 consecutive (n,strip) slots.
    int gs = (blockIdx.x & 7) * 283 + (blockIdx.x >> 3);
    if (gs > NN * 565 - 1) gs = NN * 565 - 1;
    const int n     = gs / 565;
    const int strip = gs - n * 565;
    const int pxb   = strip * 64 + wave * 16;

    const int pi    = lane & 15;        // px within wave tile
    const int dgl   = lane >> 5;        // deformable group
    const int qlow  = (lane >> 4) & 1;
    const int kgoff = dgl * 128 + qlow * 16;
    int pxs = pxb + pi;
    if (pxs > HWO - 1) pxs = HWO - 1;
    const int ho = pxs / 190;
    const int wo = pxs - ho * 190;

    const float* offp = offi + ((size_t)(n * 2 + dgl) * 9) * HWO * 2 + (size_t)pxs * 2;
    const char*  xbc  = (const char*)(xt + (size_t)n * HWc * C1c);

    v4f acc0 = {0.f,0.f,0.f,0.f}, acc1 = {0.f,0.f,0.f,0.f}, acc2 = {0.f,0.f,0.f,0.f};

    // Pipeline state. All indices below are compile-time constants.
    float2 dpre[3];      // offset (dy,dx) for taps, slot = tap % 3
    int    vaT[3][4];    // corner byte offsets, slot = tap % 3
    float  wT[3][4];     // corner weights,      slot = tap % 3
    v4i    qb[3][4];     // gather buffers,      slot = phase % 3

    dpre[0] = *(const float2*)(offp + 0 * HWO * 2);
    dpre[1] = *(const float2*)(offp + 1 * HWO * 2);

// Corner math for tap TT into slot SLOT (= TT%3); prefetch d for tap TT+2.
#define PREPT(SLOT, TT) do {                                                   \
    const int t_ = (TT);                                                       \
    const int ki_ = t_ / 3, kj_ = t_ - (t_ / 3) * 3;                           \
    float2 dv_ = dpre[SLOT];                                                   \
    float py_  = (float)(ho + ki_) + dv_.x;                                    \
    float pxf_ = (float)(wo + kj_) + dv_.y;                                    \
    float fy0_ = floorf(py_), fx0_ = floorf(pxf_);                             \
    float wy_ = py_ - fy0_, wx_ = pxf_ - fx0_;                                 \
    float fy1_ = fy0_ + 1.f, fx1_ = fx0_ + 1.f;                                \
    bool vy0_ = (fy0_ >= 0.f) && (fy0_ <= (float)(Hc - 1));                    \
    bool vy1_ = (fy1_ >= 0.f) && (fy1_ <= (float)(Hc - 1));                    \
    bool vx0_ = (fx0_ >= 0.f) && (fx0_ <= (float)(Wc - 1));                    \
    bool vx1_ = (fx1_ >= 0.f) && (fx1_ <= (float)(Wc - 1));                    \
    int iy0_ = min(max((int)fy0_, 0), Hc - 1);                                 \
    int iy1_ = min(max((int)fy1_, 0), Hc - 1);                                 \
    int ix0_ = min(max((int)fx0_, 0), Wc - 1);                                 \
    int ix1_ = min(max((int)fx1_, 0), Wc - 1);                                 \
    wT[SLOT][0] = (vy0_ && vx0_) ? (1.f - wy_) * (1.f - wx_) : 0.f;            \
    wT[SLOT][1] = (vy0_ && vx1_) ? (1.f - wy_) * wx_         : 0.f;            \
    wT[SLOT][2] = (vy1_ && vx0_) ? wy_ * (1.f - wx_)         : 0.f;            \
    wT[SLOT][3] = (vy1_ && vx1_) ? wy_ * wx_                 : 0.f;            \
    vaT[SLOT][0] = (iy0_ * Wc + ix0_) * 256 + kgoff;                           \
    vaT[SLOT][1] = (iy0_ * Wc + ix1_) * 256 + kgoff;                           \
    vaT[SLOT][2] = (iy1_ * Wc + ix0_) * 256 + kgoff;                           \
    vaT[SLOT][3] = (iy1_ * Wc + ix1_) * 256 + kgoff;                           \
    if (t_ + 2 <= 8)                                                           \
        dpre[((SLOT) + 2) % 3] = *(const float2*)(offp + (size_t)(t_ + 2) * HWO * 2); \
} while (0)

// Issue the 4 corner gathers of (tap slot SLOT, s SS) into buffer BUF.
#define ISSUEP(BUF, SLOT, SS) do {                                             \
    qb[BUF][0] = *(const v4i*)(xbc + vaT[SLOT][0] + (SS) * 32);                \
    qb[BUF][1] = *(const v4i*)(xbc + vaT[SLOT][1] + (SS) * 32);                \
    qb[BUF][2] = *(const v4i*)(xbc + vaT[SLOT][2] + (SS) * 32);                \
    qb[BUF][3] = *(const v4i*)(xbc + vaT[SLOT][3] + (SS) * 32);                \
} while (0)

// Blend one packed bf16 pair (element JJ) of buffer BUF; pack via cvt_pk.
#define BLEND1(BUF, JJ, DST) do {                                              \
    int u0_ = qb[BUF][0][JJ], u1_ = qb[BUF][1][JJ];                            \
    int u2_ = qb[BUF][2][JJ], u3_ = qb[BUF][3][JJ];                            \
    float l0_ = __builtin_bit_cast(float, u0_ << 16);                          \
    float l1_ = __builtin_bit_cast(float, u1_ << 16);                          \
    float l2_ = __builtin_bit_cast(float, u2_ << 16);                          \
    float l3_ = __builtin_bit_cast(float, u3_ << 16);                          \
    float h0_ = __builtin_bit_cast(float, (int)(u0_ & 0xffff0000));            \
    float h1_ = __builtin_bit_cast(float, (int)(u1_ & 0xffff0000));            \
    float h2_ = __builtin_bit_cast(float, (int)(u2_ & 0xffff0000));            \
    float h3_ = __builtin_bit_cast(float, (int)(u3_ & 0xffff0000));            \
    float v0_ = fmaf(W3_, l3_, fmaf(W2_, l2_, fmaf(W1_, l1_, W0_ * l0_)));     \
    float v1_ = fmaf(W3_, h3_, fmaf(W2_, h2_, fmaf(W1_, h1_, W0_ * h0_)));     \
    int r_;                                                                    \
    asm("v_cvt_pk_bf16_f32 %0, %1, %2" : "=v"(r_) : "v"(v0_), "v"(v1_));       \
    (DST) = r_;                                                                \
} while (0)

// Consume buffer BUF for (tap slot SLOT, s SS); TRT = runtime tap index.
#define CONSUMEP(BUF, SLOT, SS, TRT) do {                                      \
    const unsigned short* wtap_ = wb2 + (size_t)(TRT) * 6144;                  \
    float W0_ = wT[SLOT][0], W1_ = wT[SLOT][1];                                \
    float W2_ = wT[SLOT][2], W3_ = wT[SLOT][3];                                \
    v4i bi_;                                                                   \
    BLEND1(BUF, 0, bi_[0]);                                                    \
    BLEND1(BUF, 1, bi_[1]);                                                    \
    BLEND1(BUF, 2, bi_[2]);                                                    \
    BLEND1(BUF, 3, bi_[3]);                                                    \
    v8s bfrag_ = __builtin_bit_cast(v8s, bi_);                                 \
    v8s a0_ = *(const v8s*)(wtap_ + (0 * 4 + (SS)) * 512 + lane * 8);          \
    v8s a1_ = *(const v8s*)(wtap_ + (1 * 4 + (SS)) * 512 + lane * 8);          \
    v8s a2_ = *(const v8s*)(wtap_ + (2 * 4 + (SS)) * 512 + lane * 8);          \
    acc0 = __builtin_amdgcn_mfma_f32_16x16x32_bf16(a0_, bfrag_, acc0, 0, 0, 0);\
    acc1 = __builtin_amdgcn_mfma_f32_16x16x32_bf16(a1_, bfrag_, acc1, 0, 0, 0);\
    acc2 = __builtin_amdgcn_mfma_f32_16x16x32_bf16(a2_, bfrag_, acc2, 0, 0, 0);\
} while (0)

// Phase J of the 12-phase (3-tap) loop body. Issues phase J+2, consumes J.
// Prep runs just before the first issue of a new tap ((J+2)%4 == 0).
#define PHASE(J) do {                                                          \
    if ((J) == 2)  PREPT(1, tq3 + 1);                                          \
    if ((J) == 6)  PREPT(2, tq3 + 2);                                          \
    if ((J) == 10) { if (tq < 2) PREPT(0, tq3 + 3); }                          \
    if ((J) <= 9 || tq < 2)                                                    \
        ISSUEP(((J) + 2) % 3, (((J) + 2) >> 2) % 3, ((J) + 2) & 3);            \
    __builtin_amdgcn_sched_barrier(0);                                         \
    CONSUMEP((J) % 3, (J) >> 2, (J) & 3, tq3 + ((J) >> 2));                    \
} while (0)

    // Prologue: prep tap 0, pre-issue phases 0 and 1.
    PREPT(0, 0);
    ISSUEP(0, 0, 0);
    ISSUEP(1, 0, 1);

    #pragma unroll 1
    for (int tq = 0; tq < 3; ++tq) {
        const int tq3 = tq * 3;
        PHASE(0);  PHASE(1);  PHASE(2);  PHASE(3);
        PHASE(4);  PHASE(5);  PHASE(6);  PHASE(7);
        PHASE(8);  PHASE(9);  PHASE(10); PHASE(11);
    }

#undef PHASE
#undef CONSUMEP
#undef BLEND1
#undef ISSUEP
#undef PREPT

    // ---- epilogue: BN + Mish; C layout col=lane&15 (px), row=quad*4+reg (o)
    const int col  = lane & 15;
    const int rowq = ((lane >> 4) & 3) * 4;
    const int pxo  = pxb + col;
    if (pxo < HWO) {
        v4f accs[3] = {acc0, acc1, acc2};
        #pragma unroll
        for (int ot = 0; ot < 3; ++ot) {
            #pragma unroll
            for (int r = 0; r < 4; ++r) {
                int o = ot * 16 + rowq + r;
                if (o < 36) {
                    float inv = bn_gamma[o] * rsqrtf(bn_var[o] + 1e-5f);
                    float b   = bn_beta[o] - bn_mean[o] * inv;
                    float v   = fmaf(accs[ot][r], inv, b);
                    float sp  = (v > 20.f) ? v : log1pf(__expf(v));
                    float e2  = __expf(-2.f * sp);
                    float th  = (1.f - e2) / (1.f + e2);
                    out[((size_t)n * 36 + o) * HWO + pxo] = v * th;
                }
            }
        }
    }
}

extern "C" void kernel_launch(void* const* d_in, const int* in_sizes, int n_in,
                              void* d_out, int out_size, void* d_ws, size_t ws_size,
                              hipStream_t stream) {
    (void)in_sizes; (void)n_in; (void)out_size; (void)ws_size;
    const float* x        = (const float*)d_in[0];
    const float* conv_w   = (const float*)d_in[1];
    const float* deform_w = (const float*)d_in[2];
    const float* bn_gamma = (const float*)d_in[3];
    const float* bn_beta  = (const float*)d_in[4];
    const float* bn_mean  = (const float*)d_in[5];
    const float* bn_var   = (const float*)d_in[6];
    float* out = (float*)d_out;

    float*          offi = (float*)d_ws;                                     // 20.8 MB
    unsigned short* xt   = (unsigned short*)(offi + (size_t)NN * 36 * HWO);  // 37.7 MB
    unsigned short* wbp2 = xt + (size_t)NN * HWc * C1c;                      // 110.6 KB
    float*          cwT  = (float*)(wbp2 + (size_t)9 * 3 * 4 * 64 * 8);      // 43 KB

    x_to_nhwc<<<dim3(3, 192, 4), 256, 0, stream>>>(x, xt);
    w_prep2<<<216, 256, 0, stream>>>(deform_w, wbp2);
    cw_prep<<<42, 256, 0, stream>>>(conv_w, cwT);
    dcn_offsets<<<dim3(3, 48, 16), 256, 0, stream>>>(x, cwT, offi);
    dcn_mfma<<<dim3(8 * 283, 1), 256, 0, stream>>>(xt, wbp2, offi,
                                                   bn_gamma, bn_beta, bn_mean, bn_var, out);
}

// Round 7
// 287.127 us; speedup vs baseline: 1.7106x; 1.2365x over previous
//
#include <hip/hip_runtime.h>
#include <hip/hip_bf16.h>
#include <math.h>

#define NN     4
#define C1c    128
#define C2c    36
#define Hc     192
#define Wc     192
#define HOc    190
#define WOc    190
#define HWc    (Hc*Wc)        // 36864
#define HWO    (HOc*WOc)      // 36100

using v8s = __attribute__((ext_vector_type(8))) short;
using v4i = __attribute__((ext_vector_type(4))) int;
using v4f = __attribute__((ext_vector_type(4))) float;

__device__ __forceinline__ unsigned short f2bf(float f) {
    __hip_bfloat16 h = __float2bfloat16(f);
    return __builtin_bit_cast(unsigned short, h);
}

// ---------------- x: NCHW fp32 -> 16 sub-images of 16B records -----------
// sub = dgl*8 + qlow*4 + s  (dgl=c>>6, qlow=(c>>3)&1, s=(c>>4)&3)
// xt[((sub*NN + n)*HWc + h*Wc + w)*8 + j] = bf16 x[n][c][h][w],
//   c = dgl*64 + s*16 + qlow*8 + j  — identical channel->lane mapping as
// before; records are now 16B so a quad's 4 consecutive px read ~1 line.
__global__ void x_to_nhwc(const float* __restrict__ x, unsigned short* __restrict__ xt) {
    __shared__ float tile[64 * 129];
    const int tid = threadIdx.x;
    const int w0  = blockIdx.x * 64;
    const int h   = blockIdx.y;
    const int n   = blockIdx.z;
    {
        const int w  = tid & 63, cb = tid >> 6;
        const float* xp = x + ((size_t)n * C1c * Hc + h) * Wc + w0 + w;
        #pragma unroll
        for (int i = 0; i < 32; ++i) {
            int c = cb + i * 4;
            tile[w * 129 + c] = xp[(size_t)c * HWc];
        }
    }
    __syncthreads();
    {
        const int ww   = tid & 63;
        const int subq = tid >> 6;            // 0..3
        #pragma unroll
        for (int i = 0; i < 4; ++i) {
            int sub  = subq + i * 4;          // 0..15
            int dgl  = sub >> 3, qlow = (sub >> 2) & 1, s = sub & 3;
            int cb2  = dgl * 64 + s * 16 + qlow * 8;
            unsigned int pk[4];
            #pragma unroll
            for (int j = 0; j < 4; ++j) {
                unsigned int lo = f2bf(tile[ww * 129 + cb2 + 2 * j]);
                unsigned int hi = f2bf(tile[ww * 129 + cb2 + 2 * j + 1]);
                pk[j] = lo | (hi << 16);
            }
            size_t rec = (size_t)(sub * NN + n) * HWc + (size_t)h * Wc + w0 + ww;
            *(v4i*)(xt + rec * 8) = *(const v4i*)pk;   // 16B coalesced store
        }
    }
}

// ---------------- deform_w -> bf16 A-fragment layout (permuted K) ---------
// K permutation unchanged: k = s*32 + quad*8 + j <-> c = (quad>>1)*64 + s*16 + (quad&1)*8 + j
__global__ void w_prep2(const float* __restrict__ dw, unsigned short* __restrict__ wb2) {
    int i = blockIdx.x * 256 + threadIdx.x;
    if (i >= 9 * 3 * 4 * 64 * 8) return;
    int j    = i & 7;
    int lane = (i >> 3) & 63;
    int s    = (i >> 9) & 3;
    int rem  = i >> 11;            // tap*3 + oblk
    int oblk = rem % 3;
    int tap  = rem / 3;
    int quad = (lane >> 4) & 3;
    int o = oblk * 16 + (lane & 15);
    int c = (quad >> 1) * 64 + s * 16 + (quad & 1) * 8 + j;
    float v = (o < 36) ? dw[((size_t)o * C1c + c) * 9 + tap] : 0.f;
    wb2[i] = f2bf(v);
}

// ---------------- conv_w -> cwT[(g*32+ci)*84 + oo*9+tt] (rows padded) -----
__global__ void cw_prep(const float* __restrict__ cw, float* __restrict__ cwT) {
    int i = blockIdx.x * 256 + threadIdx.x;
    if (i >= 4 * 32 * 84) return;
    int r   = i / 84;          // g*32+ci
    int idx = i - r * 84;
    int g = r >> 5, ci = r & 31;
    float v = 0.f;
    if (idx < 81) {
        int oo = idx / 9, tt = idx - oo * 9;
        int o  = g * 9 + oo;
        v = cw[(o * 32 + ci) * 9 + tt];
    }
    cwT[i] = v;
}

// ---------------- offset conv: interleaved (dy,dx) output -----------------
__launch_bounds__(256, 8)
__global__ void dcn_offsets(const float* __restrict__ x,
                            const float* __restrict__ cwT,
                            float* __restrict__ offi) {
    const int tid = threadIdx.x;
    const int n   = blockIdx.z >> 2;
    const int g   = blockIdx.z & 3;
    int wo = blockIdx.x * 64 + (tid & 63);
    int ho = blockIdx.y * 4  + (tid >> 6);
    const bool active = (wo < WOc) && (ho < HOc);
    if (wo > WOc - 1) wo = WOc - 1;
    if (ho > HOc - 1) ho = HOc - 1;

    float offv[9];
    #pragma unroll
    for (int oo = 0; oo < 9; ++oo) offv[oo] = 0.f;

    const float* xp0 = x + ((size_t)n * C1c + g * 32) * HWc + ho * Wc + wo;
    const float* wr0 = cwT + (size_t)g * 32 * 84;
    #pragma unroll 1
    for (int ci = 0; ci < 32; ++ci) {
        const float* xp = xp0 + (size_t)ci * HWc;
        float xv[9];
        #pragma unroll
        for (int i = 0; i < 3; ++i)
            #pragma unroll
            for (int j = 0; j < 3; ++j)
                xv[i * 3 + j] = xp[i * Wc + j];
        const float* wr = wr0 + ci * 84;   // wave-uniform -> s_load
        #pragma unroll
        for (int oo = 0; oo < 9; ++oo) {
            float a = offv[oo];
            #pragma unroll
            for (int tt = 0; tt < 9; ++tt)
                a = fmaf(xv[tt], wr[oo * 9 + tt], a);
            offv[oo] = a;
        }
    }

    if (active) {
        const int px = ho * WOc + wo;
        float* base = offi + (size_t)n * 18 * HWO * 2;
        #pragma unroll
        for (int oo = 0; oo < 9; ++oo) {
            int og = g * 9 + oo;
            int dg = og / 18;
            int r  = og - dg * 18;
            int tt = r >> 1;
            int cc = r & 1;
            base[(((size_t)dg * 9 + tt) * HWO + px) * 2 + cc] = offv[oo];
        }
    }
}

// ---------------- main: s-phase pipelined gather + MFMA + BN/Mish ---------
// 36 phases (9 taps x 4 s-steps), rolling 3-buffer, lookahead 2 (as R4).
// Image now 16B-record sub-images: gather quads (4 consecutive px) read
// contiguous records -> ~1-2 cache lines per quad instead of 4.
__attribute__((amdgpu_flat_work_group_size(256, 256)))
__global__ void dcn_mfma(const unsigned short* __restrict__ xt,
                         const unsigned short* __restrict__ wb2,
                         const float* __restrict__ offi,
                         const float* __restrict__ bn_gamma,
                         const float* __restrict__ bn_beta,
                         const float* __restrict__ bn_mean,
                         const float* __restrict__ bn_var,
                         float* __restrict__ out) {
    const int tid  = threadIdx.x;
    const int lane = tid & 63;
    const int wave = tid >> 6;

    // XCD-contiguous decode: each XCD owns 283 consecutive (n,strip) slots.
    int gs = (blockIdx.x & 7) * 283 + (blockIdx.x >> 3);
    if (gs > NN * 565 - 1) gs = NN * 565 - 1;
    const int n     = gs / 565;
    const int strip = gs - n * 565;
    const int pxb   = strip * 64 + wave * 16;

    const int pi    = lane & 15;        // px within wave tile
    const int dgl   = lane >> 5;        // deformable group
    const int qlow  = (lane >> 4) & 1;
    int pxs = pxb + pi;
    if (pxs > HWO - 1) pxs = HWO - 1;
    const int ho = pxs / 190;
    const int wo = pxs - ho * 190;

    // per-lane sub-image byte bases, one per s (record = 16B)
    int kgb[4];
    #pragma unroll
    for (int s = 0; s < 4; ++s)
        kgb[s] = ((dgl * 8 + qlow * 4 + s) * NN + n) * (HWc * 16);

    const float* offp = offi + ((size_t)(n * 2 + dgl) * 9) * HWO * 2 + (size_t)pxs * 2;
    const char*  xbc  = (const char*)xt;

    v4f acc0 = {0.f,0.f,0.f,0.f}, acc1 = {0.f,0.f,0.f,0.f}, acc2 = {0.f,0.f,0.f,0.f};

    // Pipeline state. All indices below are compile-time constants.
    float2 dpre[3];      // offset (dy,dx) for taps, slot = tap % 3
    int    vaT[3][4];    // corner record byte offsets, slot = tap % 3
    float  wT[3][4];     // corner weights,             slot = tap % 3
    v4i    qb[3][4];     // gather buffers,             slot = phase % 3

    dpre[0] = *(const float2*)(offp + 0 * HWO * 2);
    dpre[1] = *(const float2*)(offp + 1 * HWO * 2);

// Corner math for tap TT into slot SLOT (= TT%3); prefetch d for tap TT+2.
#define PREPT(SLOT, TT) do {                                                   \
    const int t_ = (TT);                                                       \
    const int ki_ = t_ / 3, kj_ = t_ - (t_ / 3) * 3;                           \
    float2 dv_ = dpre[SLOT];                                                   \
    float py_  = (float)(ho + ki_) + dv_.x;                                    \
    float pxf_ = (float)(wo + kj_) + dv_.y;                                    \
    float fy0_ = floorf(py_), fx0_ = floorf(pxf_);                             \
    float wy_ = py_ - fy0_, wx_ = pxf_ - fx0_;                                 \
    float fy1_ = fy0_ + 1.f, fx1_ = fx0_ + 1.f;                                \
    bool vy0_ = (fy0_ >= 0.f) && (fy0_ <= (float)(Hc - 1));                    \
    bool vy1_ = (fy1_ >= 0.f) && (fy1_ <= (float)(Hc - 1));                    \
    bool vx0_ = (fx0_ >= 0.f) && (fx0_ <= (float)(Wc - 1));                    \
    bool vx1_ = (fx1_ >= 0.f) && (fx1_ <= (float)(Wc - 1));                    \
    int iy0_ = min(max((int)fy0_, 0), Hc - 1);                                 \
    int iy1_ = min(max((int)fy1_, 0), Hc - 1);                                 \
    int ix0_ = min(max((int)fx0_, 0), Wc - 1);                                 \
    int ix1_ = min(max((int)fx1_, 0), Wc - 1);                                 \
    wT[SLOT][0] = (vy0_ && vx0_) ? (1.f - wy_) * (1.f - wx_) : 0.f;            \
    wT[SLOT][1] = (vy0_ && vx1_) ? (1.f - wy_) * wx_         : 0.f;            \
    wT[SLOT][2] = (vy1_ && vx0_) ? wy_ * (1.f - wx_)         : 0.f;            \
    wT[SLOT][3] = (vy1_ && vx1_) ? wy_ * wx_                 : 0.f;            \
    vaT[SLOT][0] = (iy0_ * Wc + ix0_) * 16;                                    \
    vaT[SLOT][1] = (iy0_ * Wc + ix1_) * 16;                                    \
    vaT[SLOT][2] = (iy1_ * Wc + ix0_) * 16;                                    \
    vaT[SLOT][3] = (iy1_ * Wc + ix1_) * 16;                                    \
    if (t_ + 2 <= 8)                                                           \
        dpre[((SLOT) + 2) % 3] = *(const float2*)(offp + (size_t)(t_ + 2) * HWO * 2); \
} while (0)

// Issue the 4 corner gathers of (tap slot SLOT, s SS) into buffer BUF.
#define ISSUEP(BUF, SLOT, SS) do {                                             \
    qb[BUF][0] = *(const v4i*)(xbc + (size_t)(kgb[SS] + vaT[SLOT][0]));        \
    qb[BUF][1] = *(const v4i*)(xbc + (size_t)(kgb[SS] + vaT[SLOT][1]));        \
    qb[BUF][2] = *(const v4i*)(xbc + (size_t)(kgb[SS] + vaT[SLOT][2]));        \
    qb[BUF][3] = *(const v4i*)(xbc + (size_t)(kgb[SS] + vaT[SLOT][3]));        \
} while (0)

// Blend one packed bf16 pair (element JJ) of buffer BUF; pack via cvt_pk.
#define BLEND1(BUF, JJ, DST) do {                                              \
    int u0_ = qb[BUF][0][JJ], u1_ = qb[BUF][1][JJ];                            \
    int u2_ = qb[BUF][2][JJ], u3_ = qb[BUF][3][JJ];                            \
    float l0_ = __builtin_bit_cast(float, u0_ << 16);                          \
    float l1_ = __builtin_bit_cast(float, u1_ << 16);                          \
    float l2_ = __builtin_bit_cast(float, u2_ << 16);                          \
    float l3_ = __builtin_bit_cast(float, u3_ << 16);                          \
    float h0_ = __builtin_bit_cast(float, (int)(u0_ & 0xffff0000));            \
    float h1_ = __builtin_bit_cast(float, (int)(u1_ & 0xffff0000));            \
    float h2_ = __builtin_bit_cast(float, (int)(u2_ & 0xffff0000));            \
    float h3_ = __builtin_bit_cast(float, (int)(u3_ & 0xffff0000));            \
    float v0_ = fmaf(W3_, l3_, fmaf(W2_, l2_, fmaf(W1_, l1_, W0_ * l0_)));     \
    float v1_ = fmaf(W3_, h3_, fmaf(W2_, h2_, fmaf(W1_, h1_, W0_ * h0_)));     \
    int r_;                                                                    \
    asm("v_cvt_pk_bf16_f32 %0, %1, %2" : "=v"(r_) : "v"(v0_), "v"(v1_));       \
    (DST) = r_;                                                                \
} while (0)

// Consume buffer BUF for (tap slot SLOT, s SS); TRT = runtime tap index.
#define CONSUMEP(BUF, SLOT, SS, TRT) do {                                      \
    const unsigned short* wtap_ = wb2 + (size_t)(TRT) * 6144;                  \
    float W0_ = wT[SLOT][0], W1_ = wT[SLOT][1];                                \
    float W2_ = wT[SLOT][2], W3_ = wT[SLOT][3];                                \
    v4i bi_;                                                                   \
    BLEND1(BUF, 0, bi_[0]);                                                    \
    BLEND1(BUF, 1, bi_[1]);                                                    \
    BLEND1(BUF, 2, bi_[2]);                                                    \
    BLEND1(BUF, 3, bi_[3]);                                                    \
    v8s bfrag_ = __builtin_bit_cast(v8s, bi_);                                 \
    v8s a0_ = *(const v8s*)(wtap_ + (0 * 4 + (SS)) * 512 + lane * 8);          \
    v8s a1_ = *(const v8s*)(wtap_ + (1 * 4 + (SS)) * 512 + lane * 8);          \
    v8s a2_ = *(const v8s*)(wtap_ + (2 * 4 + (SS)) * 512 + lane * 8);          \
    acc0 = __builtin_amdgcn_mfma_f32_16x16x32_bf16(a0_, bfrag_, acc0, 0, 0, 0);\
    acc1 = __builtin_amdgcn_mfma_f32_16x16x32_bf16(a1_, bfrag_, acc1, 0, 0, 0);\
    acc2 = __builtin_amdgcn_mfma_f32_16x16x32_bf16(a2_, bfrag_, acc2, 0, 0, 0);\
} while (0)

// Phase J of the 12-phase (3-tap) loop body. Issues phase J+2, consumes J.
#define PHASE(J) do {                                                          \
    if ((J) == 2)  PREPT(1, tq3 + 1);                                          \
    if ((J) == 6)  PREPT(2, tq3 + 2);                                          \
    if ((J) == 10) { if (tq < 2) PREPT(0, tq3 + 3); }                          \
    if ((J) <= 9 || tq < 2)                                                    \
        ISSUEP(((J) + 2) % 3, (((J) + 2) >> 2) % 3, ((J) + 2) & 3);            \
    __builtin_amdgcn_sched_barrier(0);                                         \
    CONSUMEP((J) % 3, (J) >> 2, (J) & 3, tq3 + ((J) >> 2));                    \
} while (0)

    // Prologue: prep tap 0, pre-issue phases 0 and 1.
    PREPT(0, 0);
    ISSUEP(0, 0, 0);
    ISSUEP(1, 0, 1);

    #pragma unroll 1
    for (int tq = 0; tq < 3; ++tq) {
        const int tq3 = tq * 3;
        PHASE(0);  PHASE(1);  PHASE(2);  PHASE(3);
        PHASE(4);  PHASE(5);  PHASE(6);  PHASE(7);
        PHASE(8);  PHASE(9);  PHASE(10); PHASE(11);
    }

#undef PHASE
#undef CONSUMEP
#undef BLEND1
#undef ISSUEP
#undef PREPT

    // ---- epilogue: BN + Mish; C layout col=lane&15 (px), row=quad*4+reg (o)
    const int col  = lane & 15;
    const int rowq = ((lane >> 4) & 3) * 4;
    const int pxo  = pxb + col;
    if (pxo < HWO) {
        v4f accs[3] = {acc0, acc1, acc2};
        #pragma unroll
        for (int ot = 0; ot < 3; ++ot) {
            #pragma unroll
            for (int r = 0; r < 4; ++r) {
                int o = ot * 16 + rowq + r;
                if (o < 36) {
                    float inv = bn_gamma[o] * rsqrtf(bn_var[o] + 1e-5f);
                    float b   = bn_beta[o] - bn_mean[o] * inv;
                    float v   = fmaf(accs[ot][r], inv, b);
                    float sp  = (v > 20.f) ? v : log1pf(__expf(v));
                    float e2  = __expf(-2.f * sp);
                    float th  = (1.f - e2) / (1.f + e2);
                    out[((size_t)n * 36 + o) * HWO + pxo] = v * th;
                }
            }
        }
    }
}

extern "C" void kernel_launch(void* const* d_in, const int* in_sizes, int n_in,
                              void* d_out, int out_size, void* d_ws, size_t ws_size,
                              hipStream_t stream) {
    (void)in_sizes; (void)n_in; (void)out_size; (void)ws_size;
    const float* x        = (const float*)d_in[0];
    const float* conv_w   = (const float*)d_in[1];
    const float* deform_w = (const float*)d_in[2];
    const float* bn_gamma = (const float*)d_in[3];
    const float* bn_beta  = (const float*)d_in[4];
    const float* bn_mean  = (const float*)d_in[5];
    const float* bn_var   = (const float*)d_in[6];
    float* out = (float*)d_out;

    float*          offi = (float*)d_ws;                                     // 20.8 MB
    unsigned short* xt   = (unsigned short*)(offi + (size_t)NN * 36 * HWO);  // 37.7 MB
    unsigned short* wbp2 = xt + (size_t)NN * HWc * C1c;                      // 110.6 KB
    float*          cwT  = (float*)(wbp2 + (size_t)9 * 3 * 4 * 64 * 8);      // 43 KB

    x_to_nhwc<<<dim3(3, 192, 4), 256, 0, stream>>>(x, xt);
    w_prep2<<<216, 256, 0, stream>>>(deform_w, wbp2);
    cw_prep<<<42, 256, 0, stream>>>(conv_w, cwT);
    dcn_offsets<<<dim3(3, 48, 16), 256, 0, stream>>>(x, cwT, offi);
    dcn_mfma<<<dim3(8 * 283, 1), 256, 0, stream>>>(xt, wbp2, offi,
                                                   bn_gamma, bn_beta, bn_mean, bn_var, out);
}